// Round 2
// baseline (205.299 us; speedup 1.0000x reference)
//
#include <hip/hip_runtime.h>
#include <stdint.h>

// pairs_of_pairs: fused [concat -> conv1x1+relu x3]
// B=32, C=64, S=64, CC=128, OC=256. rows = B*(S-1) = 2016, 64 positions each.
// One block per (b,dd) row: build 64pos x 256ch bf16 tile in LDS, then 3
// chained 256x256 layers with mfma_f32_16x16x32_bf16; weights bf16 (d_ws),
// h stays in LDS. R1: 40KB LDS -> 4 blocks/CU, reg-prefetch build, f32x4
// output stores via LDS bounce.

typedef __attribute__((ext_vector_type(8))) __bf16 bf16x8;
typedef __attribute__((ext_vector_type(4))) float f32x4;
typedef __attribute__((ext_vector_type(4))) unsigned short u16x4;
typedef __attribute__((ext_vector_type(8))) unsigned short u16x8;

__device__ __forceinline__ unsigned short f2bf(float f) {
  // round-to-nearest-even fp32 -> bf16 (finite data only)
  unsigned int u = __builtin_bit_cast(unsigned int, f);
  u += 0x7FFFu + ((u >> 16) & 1u);
  return (unsigned short)(u >> 16);
}

// X element index for [pos][c] bf16 tile (64 x 256), XOR-swizzled:
// 16B-slot = pos*32 + c/8 ; slot ^= (pos&7). Kills the 512B-stride conflict.
__device__ __forceinline__ int xaddr(int pos, int c) {
  int slot = (pos << 5) + (c >> 3);
  slot ^= (pos & 7);
  return (slot << 3) + (c & 7);
}

__global__ void wconv_kernel(const float* __restrict__ W1, const float* __restrict__ W2,
                             const float* __restrict__ W3, unsigned short* __restrict__ wb) {
  int i = (blockIdx.x * 256 + threadIdx.x) * 4;  // grid 64 -> covers 65536 per layer
  const float* Ws[3] = {W1, W2, W3};
#pragma unroll
  for (int L = 0; L < 3; ++L) {
    f32x4 a = *(const f32x4*)(Ws[L] + i);
    u16x4 p;
#pragma unroll
    for (int v = 0; v < 4; ++v) p[v] = f2bf(a[v]);
    *(u16x4*)(wb + L * 65536 + i) = p;
  }
}

__global__ __launch_bounds__(256, 4)
void fused_kernel(const float* __restrict__ x, const float* __restrict__ xc,
                  const unsigned short* __restrict__ wb,
                  const float* __restrict__ b1, const float* __restrict__ b2,
                  const float* __restrict__ b3, float* __restrict__ out) {
  __shared__ __align__(16) unsigned char lraw[40960];
  unsigned short* X   = (unsigned short*)lraw;            // 32 KB [pos][c] swizzled bf16
  unsigned short* stg = (unsigned short*)(lraw + 32768);  // 8 KB [c][i] bf16 staging
  float* bounce = (float*)lraw;                           // 32 KB, reuses X for epilogue

  const int r = blockIdx.x;       // 0..2015
  const int b = r / 63;
  const int dd = r % 63;
  const int d = dd + 1;
  const int tid = threadIdx.x;
  const int lane = tid & 63;
  const int g16 = lane >> 4;      // lane group 0..3
  const int l16 = lane & 15;
  const int wv = tid >> 6;        // wave 0..3

  // ---------------- build layer-0 input tile ----------------
  // stage-chunk 0: xc ch 0..63 | 1: xc ch 64..127 | 2: x -> X chunk2 (x_rep)
  // AND X chunk3 (rolled, roll applied at transpose read).
  f32x4 ld[4];
#pragma unroll
  for (int it = 0; it < 4; ++it) {  // preload chunk 0
    int u = it * 256 + tid, cc = u >> 4, i4 = (u & 15) << 2;
    ld[it] = *(const f32x4*)(xc + (((b * 128 + cc) * 63) + dd) * 64 + i4);
  }
  for (int chunk = 0; chunk < 3; ++chunk) {
    // stage current chunk as bf16 [c][i]
#pragma unroll
    for (int it = 0; it < 4; ++it) {
      int u = it * 256 + tid, cc = u >> 4, i4 = (u & 15) << 2;
      u16x4 p;
#pragma unroll
      for (int v = 0; v < 4; ++v) p[v] = f2bf(ld[it][v]);
      *(u16x4*)&stg[cc * 64 + i4] = p;
    }
    // prefetch next chunk's globals (latency hidden across barrier+transpose)
    if (chunk < 2) {
#pragma unroll
      for (int it = 0; it < 4; ++it) {
        int u = it * 256 + tid, cc = u >> 4, i4 = (u & 15) << 2;
        const float* src = (chunk == 0)
            ? xc + (((b * 128 + 64 + cc) * 63) + dd) * 64 + i4
            : x + (b * 64 + cc) * 64 + i4;
        ld[it] = *(const f32x4*)src;
      }
    }
    __syncthreads();
    // transpose stg -> X (16B swizzled writes); chunk 2 also emits rolled chunk
    int nsub = (chunk == 2) ? 2 : 1;
    for (int sub = 0; sub < nsub; ++sub) {
      int cbase = (chunk + sub) * 64;
#pragma unroll
      for (int it = 0; it < 2; ++it) {
        int u = it * 256 + tid;
        int i = u & 63;                 // position
        int c0 = (u >> 6) << 3;         // 0,8,...,56
        int ieff = (sub == 1) ? ((i - d + 64) & 63) : i;
        u16x8 p;
#pragma unroll
        for (int j = 0; j < 8; ++j) p[j] = stg[(c0 + j) * 64 + ieff];
        *(u16x8*)&X[xaddr(i, cbase + c0)] = p;
      }
    }
    __syncthreads();
  }

  // ---------------- 3 fused conv1x1+relu layers ----------------
  for (int layer = 0; layer < 3; ++layer) {
    const unsigned short* wl = wb + layer * 65536;
    const float* bias = (layer == 0) ? b1 : (layer == 1) ? b2 : b3;

    f32x4 acc[4][4] = {};              // [mf][nf], wave tile = 64 o x 64 pos
    const int ow = wv * 64;

    for (int kk = 0; kk < 8; ++kk) {
      int kb = kk * 32 + g16 * 8;      // this lane-group's k-base (8 contiguous k)
      bf16x8 bfr[4];
#pragma unroll
      for (int nf = 0; nf < 4; ++nf)
        bfr[nf] = __builtin_bit_cast(bf16x8, *(const u16x8*)&X[xaddr(nf * 16 + l16, kb)]);
#pragma unroll
      for (int mf = 0; mf < 4; ++mf) {
        bf16x8 afr = __builtin_bit_cast(
            bf16x8, *(const u16x8*)(wl + (ow + mf * 16 + l16) * 256 + kb));
#pragma unroll
        for (int nf = 0; nf < 4; ++nf)
          acc[mf][nf] = __builtin_amdgcn_mfma_f32_16x16x32_bf16(afr, bfr[nf], acc[mf][nf], 0, 0, 0);
      }
    }
    __syncthreads();  // all waves done reading X before it is overwritten

    if (layer < 2) {
      // bias + relu -> bf16 back into X  (D frag: pos = l16 col, o = g16*4+v row)
#pragma unroll
      for (int mf = 0; mf < 4; ++mf) {
        int o0 = ow + mf * 16 + g16 * 4;
        f32x4 bv = *(const f32x4*)(bias + o0);
#pragma unroll
        for (int nf = 0; nf < 4; ++nf) {
          int pos = nf * 16 + l16;
          u16x4 p;
#pragma unroll
          for (int v = 0; v < 4; ++v)
            p[v] = f2bf(fmaxf(acc[mf][nf][v] + bv[v], 0.f));
          *(u16x4*)&X[xaddr(pos, o0)] = p;
        }
      }
      __syncthreads();
    } else {
      // final layer: bias+relu -> fp32 LDS bounce (X is dead) -> f32x4 stores.
      // Two halves of 32KB: half h covers o_local = mf(2h..2h+1) per wave.
      for (int h = 0; h < 2; ++h) {
        if (h) __syncthreads();          // h0 reads done before h1 writes
#pragma unroll
        for (int mh = 0; mh < 2; ++mh) {
          int mf = 2 * h + mh;
          int olb = mh * 16 + g16 * 4;   // o_local base (v adds 0..3)
          f32x4 bv = *(const f32x4*)(bias + ow + h * 32 + olb);
#pragma unroll
          for (int nf = 0; nf < 4; ++nf) {
            int pos = nf * 16 + l16;
#pragma unroll
            for (int v = 0; v < 4; ++v) {
              int ol = olb + v;
              bounce[(wv * 32 + ol) * 64 + (pos ^ ((ol & 7) << 2))] =
                  fmaxf(acc[mf][nf][v] + bv[v], 0.f);
            }
          }
        }
        __syncthreads();
        // read back along pos, coalesced f32x4 global stores
#pragma unroll
        for (int q = 0; q < 8; ++q) {
          int u = q * 256 + tid;
          int oh = u >> 4;               // 0..127 = wv*32 + o_local
          int pos4 = (u & 15) << 2;
          f32x4 vv = *(const f32x4*)&bounce[oh * 64 + (pos4 ^ ((oh & 7) << 2))];
          int o = (oh >> 5) * 64 + h * 32 + (oh & 31);
          *(f32x4*)&out[(((b * 256 + o) * 63) + dd) * 64 + pos4] = vv;
        }
      }
    }
  }
}

extern "C" void kernel_launch(void* const* d_in, const int* in_sizes, int n_in,
                              void* d_out, int out_size, void* d_ws, size_t ws_size,
                              hipStream_t stream) {
  const float* x  = (const float*)d_in[0];
  const float* xc = (const float*)d_in[1];
  const float* W1 = (const float*)d_in[2];
  const float* b1 = (const float*)d_in[3];
  const float* W2 = (const float*)d_in[4];
  const float* b2 = (const float*)d_in[5];
  const float* W3 = (const float*)d_in[6];
  const float* b3 = (const float*)d_in[7];
  float* out = (float*)d_out;
  unsigned short* wb = (unsigned short*)d_ws;  // 3 x 256 x 256 bf16 = 384 KB

  wconv_kernel<<<64, 256, 0, stream>>>(W1, W2, W3, wb);
  fused_kernel<<<2016, 256, 0, stream>>>(x, xc, wb, b1, b2, b3, out);
}

// Round 3
// 122.621 us; speedup vs baseline: 1.6742x; 1.6742x over previous
//
#include <hip/hip_runtime.h>
#include <stdint.h>

// pairs_of_pairs: fused [concat -> conv1x1+relu x3]
// B=32, C=64, S=64, CC=128, OC=256. rows = B*(S-1) = 2016, 64 positions each.
// R2: 512-thread blocks (8 waves), wave tile 32o x 64pos (acc = 32 regs) so
// 2 blocks/CU fit WITHOUT spills (R1 lesson: forced 64-VGPR cap spilled
// ~400MB to scratch). LDS 40KB: X 32KB [pos][c] swizzled bf16 + stg 8KB.

typedef __attribute__((ext_vector_type(8))) __bf16 bf16x8;
typedef __attribute__((ext_vector_type(4))) float f32x4;
typedef __attribute__((ext_vector_type(4))) unsigned short u16x4;
typedef __attribute__((ext_vector_type(8))) unsigned short u16x8;

__device__ __forceinline__ unsigned short f2bf(float f) {
  unsigned int u = __builtin_bit_cast(unsigned int, f);
  u += 0x7FFFu + ((u >> 16) & 1u);
  return (unsigned short)(u >> 16);
}

// X element index for [pos][c] bf16 tile (64 x 256), XOR-swizzled:
// 16B-slot = pos*32 + c/8 ; slot ^= (pos&7). Kills the 512B-stride conflict.
__device__ __forceinline__ int xaddr(int pos, int c) {
  int slot = (pos << 5) + (c >> 3);
  slot ^= (pos & 7);
  return (slot << 3) + (c & 7);
}

__global__ void wconv_kernel(const float* __restrict__ W1, const float* __restrict__ W2,
                             const float* __restrict__ W3, unsigned short* __restrict__ wb) {
  int i = (blockIdx.x * 256 + threadIdx.x) * 4;  // grid 64 -> 65536 per layer
  const float* Ws[3] = {W1, W2, W3};
#pragma unroll
  for (int L = 0; L < 3; ++L) {
    f32x4 a = *(const f32x4*)(Ws[L] + i);
    u16x4 p;
#pragma unroll
    for (int v = 0; v < 4; ++v) p[v] = f2bf(a[v]);
    *(u16x4*)(wb + L * 65536 + i) = p;
  }
}

__global__ __launch_bounds__(512, 2)
void fused_kernel(const float* __restrict__ x, const float* __restrict__ xc,
                  const unsigned short* __restrict__ wb,
                  const float* __restrict__ b1, const float* __restrict__ b2,
                  const float* __restrict__ b3, float* __restrict__ out) {
  __shared__ __align__(16) unsigned char lraw[40960];
  unsigned short* X   = (unsigned short*)lraw;            // 32 KB [pos][c] swizzled
  unsigned short* stg = (unsigned short*)(lraw + 32768);  // 8 KB [c][i] bf16 staging
  float* bounce = (float*)lraw;                           // reuses X for epilogue

  const int r = blockIdx.x;       // 0..2015
  const int b = r / 63;
  const int dd = r % 63;
  const int d = dd + 1;
  const int tid = threadIdx.x;    // 0..511
  const int lane = tid & 63;
  const int g16 = lane >> 4;
  const int l16 = lane & 15;
  const int wv = tid >> 6;        // wave 0..7

  // ---------------- build layer-0 input tile ----------------
  // stage-chunk 0: xc ch 0..63 | 1: xc ch 64..127 | 2: x -> X chunk2 (x_rep)
  // AND X chunk3 (rolled, roll applied at transpose read).
  f32x4 ld[2];
#pragma unroll
  for (int it = 0; it < 2; ++it) {  // preload chunk 0
    int u = it * 512 + tid, cc = u >> 4, i4 = (u & 15) << 2;
    ld[it] = *(const f32x4*)(xc + (((b * 128 + cc) * 63) + dd) * 64 + i4);
  }
  for (int chunk = 0; chunk < 3; ++chunk) {
#pragma unroll
    for (int it = 0; it < 2; ++it) {
      int u = it * 512 + tid, cc = u >> 4, i4 = (u & 15) << 2;
      u16x4 p;
#pragma unroll
      for (int v = 0; v < 4; ++v) p[v] = f2bf(ld[it][v]);
      *(u16x4*)&stg[cc * 64 + i4] = p;
    }
    if (chunk < 2) {  // prefetch next chunk (latency hidden across barrier)
#pragma unroll
      for (int it = 0; it < 2; ++it) {
        int u = it * 512 + tid, cc = u >> 4, i4 = (u & 15) << 2;
        const float* src = (chunk == 0)
            ? xc + (((b * 128 + 64 + cc) * 63) + dd) * 64 + i4
            : x + (b * 64 + cc) * 64 + i4;
        ld[it] = *(const f32x4*)src;
      }
    }
    __syncthreads();
    // transpose stg -> X; chunk 2 also emits rolled chunk 3
    int nsub = (chunk == 2) ? 2 : 1;
    for (int sub = 0; sub < nsub; ++sub) {
      int cbase = (chunk + sub) * 64;
      int i = tid & 63;               // position
      int c0 = (tid >> 6) << 3;       // 0,8,...,56
      int ieff = (sub == 1) ? ((i - d + 64) & 63) : i;
      u16x8 p;
#pragma unroll
      for (int j = 0; j < 8; ++j) p[j] = stg[(c0 + j) * 64 + ieff];
      *(u16x8*)&X[xaddr(i, cbase + c0)] = p;
    }
    __syncthreads();
  }

  // ---------------- 3 fused conv1x1+relu layers ----------------
  for (int layer = 0; layer < 3; ++layer) {
    const unsigned short* wl = wb + layer * 65536;
    const float* bias = (layer == 0) ? b1 : (layer == 1) ? b2 : b3;

    f32x4 acc[2][4] = {};              // [mf][nf], wave tile = 32 o x 64 pos
    const int ow = wv * 32;

#pragma unroll 2
    for (int kk = 0; kk < 8; ++kk) {
      int kb = kk * 32 + g16 * 8;      // this lane-group's k-base
      bf16x8 bfr[4];
#pragma unroll
      for (int nf = 0; nf < 4; ++nf)
        bfr[nf] = __builtin_bit_cast(bf16x8, *(const u16x8*)&X[xaddr(nf * 16 + l16, kb)]);
#pragma unroll
      for (int mf = 0; mf < 2; ++mf) {
        bf16x8 afr = __builtin_bit_cast(
            bf16x8, *(const u16x8*)(wl + (ow + mf * 16 + l16) * 256 + kb));
#pragma unroll
        for (int nf = 0; nf < 4; ++nf)
          acc[mf][nf] = __builtin_amdgcn_mfma_f32_16x16x32_bf16(afr, bfr[nf], acc[mf][nf], 0, 0, 0);
      }
    }
    __syncthreads();  // all waves done reading X before it is overwritten

    if (layer < 2) {
      // bias + relu -> bf16 back into X  (D frag: pos = l16 col, o = g16*4+v row)
#pragma unroll
      for (int mf = 0; mf < 2; ++mf) {
        int o0 = ow + mf * 16 + g16 * 4;
        f32x4 bv = *(const f32x4*)(bias + o0);
#pragma unroll
        for (int nf = 0; nf < 4; ++nf) {
          int pos = nf * 16 + l16;
          u16x4 p;
#pragma unroll
          for (int v = 0; v < 4; ++v)
            p[v] = f2bf(fmaxf(acc[mf][nf][v] + bv[v], 0.f));
          *(u16x4*)&X[xaddr(pos, o0)] = p;
        }
      }
      __syncthreads();
    } else {
      // final layer: bias+relu -> fp32 LDS bounce (X dead) -> f32x4 stores.
      // half h covers o in [h*128, h*128+128), produced by waves wv>>2 == h.
      for (int h = 0; h < 2; ++h) {
        if (h) __syncthreads();          // h0 reads done before h1 writes
        if ((wv >> 2) == h) {
#pragma unroll
          for (int mf = 0; mf < 2; ++mf) {
            int olb = (wv & 3) * 32 + mf * 16 + g16 * 4;  // o_local base
            f32x4 bv = *(const f32x4*)(bias + h * 128 + olb);
#pragma unroll
            for (int nf = 0; nf < 4; ++nf) {
              int pos = nf * 16 + l16;
#pragma unroll
              for (int v = 0; v < 4; ++v) {
                int ol = olb + v;
                bounce[ol * 64 + (pos ^ ((ol & 7) << 2))] =
                    fmaxf(acc[mf][nf][v] + bv[v], 0.f);
              }
            }
          }
        }
        __syncthreads();
        // read back along pos, coalesced f32x4 global stores
#pragma unroll
        for (int q = 0; q < 4; ++q) {
          int u = q * 512 + tid;
          int oh = u >> 4;               // 0..127
          int pos4 = (u & 15) << 2;
          f32x4 vv = *(const f32x4*)&bounce[oh * 64 + (pos4 ^ ((oh & 7) << 2))];
          int o = h * 128 + oh;
          *(f32x4*)&out[(((b * 256 + o) * 63) + dd) * 64 + pos4] = vv;
        }
      }
    }
  }
}

extern "C" void kernel_launch(void* const* d_in, const int* in_sizes, int n_in,
                              void* d_out, int out_size, void* d_ws, size_t ws_size,
                              hipStream_t stream) {
  const float* x  = (const float*)d_in[0];
  const float* xc = (const float*)d_in[1];
  const float* W1 = (const float*)d_in[2];
  const float* b1 = (const float*)d_in[3];
  const float* W2 = (const float*)d_in[4];
  const float* b2 = (const float*)d_in[5];
  const float* W3 = (const float*)d_in[6];
  const float* b3 = (const float*)d_in[7];
  float* out = (float*)d_out;
  unsigned short* wb = (unsigned short*)d_ws;  // 3 x 256 x 256 bf16 = 384 KB

  wconv_kernel<<<64, 256, 0, stream>>>(W1, W2, W3, wb);
  fused_kernel<<<2016, 512, 0, stream>>>(x, xc, wb, b1, b2, b3, out);
}

// Round 4
// 110.393 us; speedup vs baseline: 1.8597x; 1.1108x over previous
//
#include <hip/hip_runtime.h>
#include <stdint.h>

// pairs_of_pairs: fused [concat -> conv1x1+relu x3]
// B=32, C=64, S=64, CC=128, OC=256. 2016 rows of 64 positions.
// R3: 2 rows per block (rows (b0,dd) and (b0+16,dd)), grid 1008.
// Per kk-iter: 2 weight loads feed 16 MFMA (2x arithmetic intensity vs R2's
// 8), barriers per unit work -25%. LDS 72KB (X 64KB = 128pos x 256ch bf16,
// swizzled + stg 8KB) -> 2 blocks/CU. acc[2][8]=64 regs, target <=128 VGPR.

typedef __attribute__((ext_vector_type(8))) __bf16 bf16x8;
typedef __attribute__((ext_vector_type(4))) float f32x4;
typedef __attribute__((ext_vector_type(4))) unsigned short u16x4;
typedef __attribute__((ext_vector_type(8))) unsigned short u16x8;

__device__ __forceinline__ unsigned short f2bf(float f) {
  unsigned int u = __builtin_bit_cast(unsigned int, f);
  u += 0x7FFFu + ((u >> 16) & 1u);
  return (unsigned short)(u >> 16);
}

// X element index for [pos][c] bf16 tile (128 x 256), XOR-swizzled:
// 16B-slot = pos*32 + c/8 ; slot ^= (pos&7). Kills the 512B-stride conflict.
__device__ __forceinline__ int xaddr(int pos, int c) {
  int slot = (pos << 5) + (c >> 3);
  slot ^= (pos & 7);
  return (slot << 3) + (c & 7);
}

__global__ void wconv_kernel(const float* __restrict__ W1, const float* __restrict__ W2,
                             const float* __restrict__ W3, unsigned short* __restrict__ wb) {
  int i = (blockIdx.x * 256 + threadIdx.x) * 4;  // grid 64 -> 65536 per layer
  const float* Ws[3] = {W1, W2, W3};
#pragma unroll
  for (int L = 0; L < 3; ++L) {
    f32x4 a = *(const f32x4*)(Ws[L] + i);
    u16x4 p;
#pragma unroll
    for (int v = 0; v < 4; ++v) p[v] = f2bf(a[v]);
    *(u16x4*)(wb + L * 65536 + i) = p;
  }
}

__global__ __launch_bounds__(512, 2)
void fused_kernel(const float* __restrict__ x, const float* __restrict__ xc,
                  const unsigned short* __restrict__ wb,
                  const float* __restrict__ b1, const float* __restrict__ b2,
                  const float* __restrict__ b3, float* __restrict__ out) {
  __shared__ __align__(16) unsigned char lraw[73728];
  unsigned short* X   = (unsigned short*)lraw;            // 64 KB [pos][c] swizzled
  unsigned short* stg = (unsigned short*)(lraw + 65536);  // 8 KB [c][i] bf16 staging
  float* bounce = (float*)lraw;                           // 32 KB, reuses X (epilogue)

  const int r = blockIdx.x;       // 0..1007
  const int b0 = r / 63;          // 0..15 ; row1 uses b0+16
  const int dd = r % 63;
  const int d = dd + 1;
  const int tid = threadIdx.x;    // 0..511
  const int lane = tid & 63;
  const int g16 = lane >> 4;
  const int l16 = lane & 15;
  const int wv = tid >> 6;        // wave 0..7

  // ---------------- build layer-0 input tiles (2 rows) ----------------
  // 6 stage rounds: rounds 0-2 row0 (b0), rounds 3-5 row1 (b0+16).
  // round%3: 0 -> xc ch 0..63 | 1 -> xc ch 64..127 | 2 -> x (emits x_rep
  // chunk AND rolled chunk, roll applied at transpose read).
  auto ldrnd = [&](int rd, f32x4 ld[2]) {
    int rr = rd / 3;
    int ck = rd - rr * 3;
    int b = b0 + 16 * rr;
#pragma unroll
    for (int it = 0; it < 2; ++it) {
      int u = it * 512 + tid, cc = u >> 4, i4 = (u & 15) << 2;
      const float* src = (ck < 2)
          ? xc + (((b * 128 + ck * 64 + cc) * 63) + dd) * 64 + i4
          : x + (b * 64 + cc) * 64 + i4;
      ld[it] = *(const f32x4*)src;
    }
  };

  f32x4 ld[2];
  ldrnd(0, ld);
  for (int rd = 0; rd < 6; ++rd) {
    int rr = rd / 3;
    int ck = rd - rr * 3;
#pragma unroll
    for (int it = 0; it < 2; ++it) {   // regs -> stg (bf16 [c][i])
      int u = it * 512 + tid, cc = u >> 4, i4 = (u & 15) << 2;
      u16x4 p;
#pragma unroll
      for (int v = 0; v < 4; ++v) p[v] = f2bf(ld[it][v]);
      *(u16x4*)&stg[cc * 64 + i4] = p;
    }
    if (rd < 5) ldrnd(rd + 1, ld);     // prefetch next round's globals
    __syncthreads();
    // transpose stg -> X rows [rr*64, rr*64+64)
    int nsub = (ck == 2) ? 2 : 1;
    for (int sub = 0; sub < nsub; ++sub) {
      int cbase = (ck + sub) * 64;
      int i = tid & 63;                // position within row
      int c0 = (tid >> 6) << 3;        // 0,8,...,56
      int ieff = (sub == 1) ? ((i - d + 64) & 63) : i;
      u16x8 p;
#pragma unroll
      for (int j = 0; j < 8; ++j) p[j] = stg[(c0 + j) * 64 + ieff];
      *(u16x8*)&X[xaddr(rr * 64 + i, cbase + c0)] = p;
    }
    __syncthreads();
  }

  // ---------------- 3 fused conv1x1+relu layers ----------------
  for (int layer = 0; layer < 3; ++layer) {
    const unsigned short* wl = wb + layer * 65536;
    const float* bias = (layer == 0) ? b1 : (layer == 1) ? b2 : b3;

    f32x4 acc[2][8] = {};              // [mf][nf], wave tile = 32 o x 128 pos
    const int ow = wv * 32;

#pragma unroll 2
    for (int kk = 0; kk < 8; ++kk) {
      int kb = kk * 32 + g16 * 8;      // this lane-group's k-base
      bf16x8 afr[2];
#pragma unroll
      for (int mf = 0; mf < 2; ++mf)
        afr[mf] = __builtin_bit_cast(
            bf16x8, *(const u16x8*)(wl + (ow + mf * 16 + l16) * 256 + kb));
      bf16x8 bfr[4];
#pragma unroll
      for (int nf = 0; nf < 4; ++nf)   // row0 positions 0..63
        bfr[nf] = __builtin_bit_cast(bf16x8, *(const u16x8*)&X[xaddr(nf * 16 + l16, kb)]);
#pragma unroll
      for (int mf = 0; mf < 2; ++mf)
#pragma unroll
        for (int nf = 0; nf < 4; ++nf)
          acc[mf][nf] = __builtin_amdgcn_mfma_f32_16x16x32_bf16(afr[mf], bfr[nf], acc[mf][nf], 0, 0, 0);
#pragma unroll
      for (int nf = 0; nf < 4; ++nf)   // row1 positions 64..127
        bfr[nf] = __builtin_bit_cast(bf16x8, *(const u16x8*)&X[xaddr(64 + nf * 16 + l16, kb)]);
#pragma unroll
      for (int mf = 0; mf < 2; ++mf)
#pragma unroll
        for (int nf = 0; nf < 4; ++nf)
          acc[mf][4 + nf] = __builtin_amdgcn_mfma_f32_16x16x32_bf16(afr[mf], bfr[nf], acc[mf][4 + nf], 0, 0, 0);
    }
    __syncthreads();  // all waves done reading X before it is overwritten

    if (layer < 2) {
      // bias + relu -> bf16 back into X (D frag: pos = l16 col, o = g16*4+v)
#pragma unroll
      for (int mf = 0; mf < 2; ++mf) {
        int o0 = ow + mf * 16 + g16 * 4;
        f32x4 bv = *(const f32x4*)(bias + o0);
#pragma unroll
        for (int nf = 0; nf < 8; ++nf) {
          int pos = nf * 16 + l16;     // 0..127 covers both rows
          u16x4 p;
#pragma unroll
          for (int v = 0; v < 4; ++v)
            p[v] = f2bf(fmaxf(acc[mf][nf][v] + bv[v], 0.f));
          *(u16x4*)&X[xaddr(pos, o0)] = p;
        }
      }
      __syncthreads();
    } else {
      // final: bias+relu -> fp32 LDS bounce (X dead) -> f32x4 stores.
      // 4 rounds (rr,h): row rr, o in [h*128, h*128+128). Waves wv>>2==h write.
      bool first = true;
#pragma unroll
      for (int rr = 0; rr < 2; ++rr) {
#pragma unroll
        for (int h = 0; h < 2; ++h) {
          if (!first) __syncthreads();   // prev round's reads done
          first = false;
          if ((wv >> 2) == h) {
#pragma unroll
            for (int mf = 0; mf < 2; ++mf) {
              int olb = (wv & 3) * 32 + mf * 16 + g16 * 4;  // o - h*128
              f32x4 bv = *(const f32x4*)(bias + h * 128 + olb);
#pragma unroll
              for (int nq = 0; nq < 4; ++nq) {
                int pos = nq * 16 + l16;  // within-row position
#pragma unroll
                for (int v = 0; v < 4; ++v) {
                  int ol = olb + v;
                  bounce[ol * 64 + (pos ^ ((ol & 7) << 2))] =
                      fmaxf(acc[mf][rr * 4 + nq][v] + bv[v], 0.f);
                }
              }
            }
          }
          __syncthreads();
          // read back along pos, coalesced f32x4 global stores
          int bq = b0 + 16 * rr;
#pragma unroll
          for (int q = 0; q < 4; ++q) {
            int u = q * 512 + tid;
            int oh = u >> 4;             // 0..127
            int pos4 = (u & 15) << 2;
            f32x4 vv = *(const f32x4*)&bounce[oh * 64 + (pos4 ^ ((oh & 7) << 2))];
            int o = h * 128 + oh;
            *(f32x4*)&out[(((bq * 256 + o) * 63) + dd) * 64 + pos4] = vv;
          }
        }
      }
    }
  }
}

extern "C" void kernel_launch(void* const* d_in, const int* in_sizes, int n_in,
                              void* d_out, int out_size, void* d_ws, size_t ws_size,
                              hipStream_t stream) {
  const float* x  = (const float*)d_in[0];
  const float* xc = (const float*)d_in[1];
  const float* W1 = (const float*)d_in[2];
  const float* b1 = (const float*)d_in[3];
  const float* W2 = (const float*)d_in[4];
  const float* b2 = (const float*)d_in[5];
  const float* W3 = (const float*)d_in[6];
  const float* b3 = (const float*)d_in[7];
  float* out = (float*)d_out;
  unsigned short* wb = (unsigned short*)d_ws;  // 3 x 256 x 256 bf16 = 384 KB

  wconv_kernel<<<64, 256, 0, stream>>>(W1, W2, W3, wb);
  fused_kernel<<<1008, 512, 0, stream>>>(x, xc, wb, b1, b2, b3, out);
}